// Round 3
// baseline (15.494 us; speedup 1.0000x reference)
//
#include <hip/hip_runtime.h>

// CombinedLoss_88450556494045 — 5-level annotation assignment, v3.
// Block-level candidate window via __syncthreads_count (no binary search),
// broadcast LDS scan (all lanes same j), 4 anchors/thread, float4 stores.
//
// Output layout (f32 elements), N = 253952:
//   pos[0,N) assigned[N,4N) norm[4N,7N) ls[7N,8N) rs[8N,9N)
//   nls[9N,10N) nrs[10N,11N) levels[11N,12N)

#define N_TOTAL 253952
#define INF_VAL 1.0e8f

__global__ __launch_bounds__(256) void assign_levels_v3(
    const float* __restrict__ ann,
    float* __restrict__ out)
{
    __shared__ float4 sA[256];  // {l, m=min(r,l+radius*stride), area=r-l, r}
    __shared__ float  sC[256];  // cls

    const int b = blockIdx.x;
    int level, blockBase, gBase;
    float loC, hiC, stride;
    // TARGET_RATE = 22050/256 = 86.1328125 ; edges = midpoints of CLUSTERS
    if (b < 128)      { level=0; blockBase=0;   gBase=0;      stride=1.0f;
                        loC=(float)(-1.0*86.1328125);  hiC=(float)(0.525*86.1328125); }
    else if (b < 192) { level=1; blockBase=128; gBase=131072; stride=2.0f;
                        loC=(float)(0.525*86.1328125); hiC=(float)(1.05*86.1328125); }
    else if (b < 224) { level=2; blockBase=192; gBase=196608; stride=4.0f;
                        loC=(float)(1.05*86.1328125);  hiC=(float)(2.1*86.1328125); }
    else if (b < 240) { level=3; blockBase=224; gBase=229376; stride=8.0f;
                        loC=(float)(2.1*86.1328125);   hiC=(float)(4.2*86.1328125); }
    else              { level=4; blockBase=240; gBase=245760; stride=16.0f;
                        loC=(float)(4.2*86.1328125);   hiC=(float)(1000.0*86.1328125); }

    const int t = threadIdx.x;
    float l, r, c;
    {
        l = ann[3*t+0]; r = ann[3*t+1]; c = ann[3*t+2];
        float radius = (c == 0.0f ? 4.5f : 0.0f) + (c == 1.0f ? 2.5f : 0.0f);
        float limit = l + radius * stride;     // radius*stride exact in fp32
        sA[t] = make_float4(l, fminf(r, limit), r - l, r);
        sC[t] = c;
    }

    // Block anchor range: indices [firstIdx, firstIdx+1023]
    const int firstIdx = (b - blockBase) * 1024;
    const float aFirst = ((float)firstIdx + 0.5f) * stride;
    const float aLast  = ((float)(firstIdx + 1023) + 0.5f) * stride;
    // Any valid annotation: l <= a <= r = l + area < l + 517
    const float aMinB = aFirst - 520.0f;

    // Candidate window over sorted l (counts across the block's 256 threads,
    // one annotation per thread). These also serve as the LDS barrier.
    const int winLo = __syncthreads_count(l < aMinB);
    const int winHi = __syncthreads_count(l <= aLast);

    const int i0 = firstIdx + t * 4;           // first of 4 anchors
    const float inv = 1.0f / stride;           // exact 2^-i

    const float a0 = ((float)(i0 + 0) + 0.5f) * stride;
    const float a1 = ((float)(i0 + 1) + 0.5f) * stride;
    const float a2 = ((float)(i0 + 2) + 0.5f) * stride;
    const float a3 = ((float)(i0 + 3) + 0.5f) * stride;

    float best0 = INF_VAL, best1 = INF_VAL, best2 = INF_VAL, best3 = INF_VAL;
    int   idx0 = 0, idx1 = 0, idx2 = 0, idx3 = 0;

    for (int j = winLo; j < winHi; ++j) {
        const float4 q = sA[j];                // broadcast: same j on all lanes
        // ascending scan + strict '<' => first index of min (argmin semantics)
        {
            float mx = fmaxf(a0 - q.x, q.w - a0);
            bool ok = (a0 >= q.x) & (a0 <= q.y) & (mx >= loC) & (mx <= hiC);
            if (ok & (q.z < best0)) { best0 = q.z; idx0 = j; }
        }
        {
            float mx = fmaxf(a1 - q.x, q.w - a1);
            bool ok = (a1 >= q.x) & (a1 <= q.y) & (mx >= loC) & (mx <= hiC);
            if (ok & (q.z < best1)) { best1 = q.z; idx1 = j; }
        }
        {
            float mx = fmaxf(a2 - q.x, q.w - a2);
            bool ok = (a2 >= q.x) & (a2 <= q.y) & (mx >= loC) & (mx <= hiC);
            if (ok & (q.z < best2)) { best2 = q.z; idx2 = j; }
        }
        {
            float mx = fmaxf(a3 - q.x, q.w - a3);
            bool ok = (a3 >= q.x) & (a3 <= q.y) & (mx >= loC) & (mx <= hiC);
            if (ok & (q.z < best3)) { best3 = q.z; idx3 = j; }
        }
    }

    float ps[4], lb[4], rb[4], cl[4], lsv[4], rsv[4];
    const float aN[4] = {a0, a1, a2, a3};
    const float bst[4] = {best0, best1, best2, best3};
    const int   bix[4] = {idx0, idx1, idx2, idx3};
    #pragma unroll
    for (int k = 0; k < 4; ++k) {
        const float4 qb = sA[bix[k]];
        const bool pos = bst[k] < INF_VAL;
        ps[k]  = pos ? 1.0f : 0.0f;
        lb[k]  = qb.x;
        rb[k]  = qb.w;
        cl[k]  = pos ? sC[bix[k]] : 0.0f;
        lsv[k] = aN[k] - qb.x;
        rsv[k] = qb.w - aN[k];
    }

    const int g = gBase + i0;   // multiple of 4 -> all float4 stores aligned

    *(float4*)(out + g) = make_float4(ps[0], ps[1], ps[2], ps[3]);

    float* A = out + N_TOTAL + 3*g;
    *(float4*)(A + 0) = make_float4(lb[0], rb[0], cl[0], lb[1]);
    *(float4*)(A + 4) = make_float4(rb[1], cl[1], lb[2], rb[2]);
    *(float4*)(A + 8) = make_float4(cl[2], lb[3], rb[3], cl[3]);

    float* Nm = out + 4*N_TOTAL + 3*g;
    *(float4*)(Nm + 0) = make_float4(lb[0]*inv, rb[0]*inv, cl[0],     lb[1]*inv);
    *(float4*)(Nm + 4) = make_float4(rb[1]*inv, cl[1],     lb[2]*inv, rb[2]*inv);
    *(float4*)(Nm + 8) = make_float4(cl[2],     lb[3]*inv, rb[3]*inv, cl[3]);

    *(float4*)(out + 7*N_TOTAL  + g) = make_float4(lsv[0], lsv[1], lsv[2], lsv[3]);
    *(float4*)(out + 8*N_TOTAL  + g) = make_float4(rsv[0], rsv[1], rsv[2], rsv[3]);
    *(float4*)(out + 9*N_TOTAL  + g) = make_float4(lsv[0]*inv, lsv[1]*inv, lsv[2]*inv, lsv[3]*inv);
    *(float4*)(out + 10*N_TOTAL + g) = make_float4(rsv[0]*inv, rsv[1]*inv, rsv[2]*inv, rsv[3]*inv);

    const float lv = (float)(level + 1);
    *(float4*)(out + 11*N_TOTAL + g) = make_float4(lv, lv, lv, lv);
}

extern "C" void kernel_launch(void* const* d_in, const int* in_sizes, int n_in,
                              void* d_out, int out_size, void* d_ws, size_t ws_size,
                              hipStream_t stream) {
    const float* ann = (const float*)d_in[0];
    float* out = (float*)d_out;
    assign_levels_v3<<<248, 256, 0, stream>>>(ann, out);
}

// Round 4
// 10.567 us; speedup vs baseline: 1.4663x; 1.4663x over previous
//
#include <hip/hip_runtime.h>

// CombinedLoss_88450556494045 — 5-level annotation assignment, v4.
// v1's grid shape (992 blocks, 1 anchor/thread, coalesced scalar stores) +
// v3's block-uniform broadcast window (no per-thread binary search) +
// analytic anchors (no anchor loads).
//
// Output layout (f32 elements), N = 253952:
//   pos[0,N) assigned[N,4N) norm[4N,7N) ls[7N,8N) rs[8N,9N)
//   nls[9N,10N) nrs[10N,11N) levels[11N,12N)

#define N_TOTAL 253952
#define INF_VAL 1.0e8f

__global__ __launch_bounds__(256) void assign_levels_v4(
    const float* __restrict__ ann,
    float* __restrict__ out)
{
    __shared__ float4 sA[256];  // {l, m=min(r,l+radius*stride), area=r-l, r}
    __shared__ float  sC[256];  // cls

    const int b = blockIdx.x;
    int level, blockBase, gBase;
    float loC, hiC, stride;
    // TARGET_RATE = 22050/256 = 86.1328125 ; edges = midpoints of CLUSTERS
    if (b < 512)      { level=0; blockBase=0;   gBase=0;      stride=1.0f;
                        loC=(float)(-1.0*86.1328125);  hiC=(float)(0.525*86.1328125); }
    else if (b < 768) { level=1; blockBase=512; gBase=131072; stride=2.0f;
                        loC=(float)(0.525*86.1328125); hiC=(float)(1.05*86.1328125); }
    else if (b < 896) { level=2; blockBase=768; gBase=196608; stride=4.0f;
                        loC=(float)(1.05*86.1328125);  hiC=(float)(2.1*86.1328125); }
    else if (b < 960) { level=3; blockBase=896; gBase=229376; stride=8.0f;
                        loC=(float)(2.1*86.1328125);   hiC=(float)(4.2*86.1328125); }
    else              { level=4; blockBase=960; gBase=245760; stride=16.0f;
                        loC=(float)(4.2*86.1328125);   hiC=(float)(1000.0*86.1328125); }

    const int t = threadIdx.x;
    float l;
    {
        l = ann[3*t+0];
        float r = ann[3*t+1], c = ann[3*t+2];
        float radius = (c == 0.0f ? 4.5f : 0.0f) + (c == 1.0f ? 2.5f : 0.0f);
        float limit = l + radius * stride;     // radius*stride exact in fp32
        sA[t] = make_float4(l, fminf(r, limit), r - l, r);
        sC[t] = c;
    }

    // Block's anchors: indices [firstIdx, firstIdx+255] in this level
    const int firstIdx = (b - blockBase) * 256;
    const float aFirst = ((float)firstIdx + 0.5f) * stride;          // exact
    const float aLast  = ((float)(firstIdx + 255) + 0.5f) * stride;  // exact
    // Valid annotation needs l <= a <= r < l + 517 (max dur 6*86.13=516.8)
    const float aMinB = aFirst - 520.0f;

    // Candidate window over sorted l; the two counts double as LDS barriers.
    const int winLo = __syncthreads_count(l < aMinB);
    const int winHi = __syncthreads_count(l <= aLast);

    const int idxInLevel = firstIdx + t;
    const float a = ((float)idxInLevel + 0.5f) * stride;  // bit-exact anchor
    const float inv = 1.0f / stride;                      // exact 2^-i

    float best = INF_VAL;
    int bidx = 0;
    for (int j = winLo; j < winHi; ++j) {
        const float4 q = sA[j];          // same j on all lanes -> broadcast
        float mx = fmaxf(a - q.x, q.w - a);
        bool ok = (a >= q.x) & (a <= q.y) & (mx >= loC) & (mx <= hiC);
        // ascending + strict '<' => first index of min (argmin semantics)
        if (ok & (q.z < best)) { best = q.z; bidx = j; }
    }

    const float4 qb  = sA[bidx];
    const bool  pos  = best < INF_VAL;
    const float clsOut = pos ? sC[bidx] : 0.0f;
    const float lb = qb.x, rb = qb.w;
    const float lsv = a - lb;
    const float rsv = rb - a;
    const int g = gBase + idxInLevel;

    out[g] = pos ? 1.0f : 0.0f;
    float* A = out + N_TOTAL + 3*g;
    A[0] = lb; A[1] = rb; A[2] = clsOut;
    float* Nm = out + 4*N_TOTAL + 3*g;
    Nm[0] = lb * inv; Nm[1] = rb * inv; Nm[2] = clsOut;
    out[7*N_TOTAL  + g] = lsv;
    out[8*N_TOTAL  + g] = rsv;
    out[9*N_TOTAL  + g] = lsv * inv;
    out[10*N_TOTAL + g] = rsv * inv;
    out[11*N_TOTAL + g] = (float)(level + 1);
}

extern "C" void kernel_launch(void* const* d_in, const int* in_sizes, int n_in,
                              void* d_out, int out_size, void* d_ws, size_t ws_size,
                              hipStream_t stream) {
    const float* ann = (const float*)d_in[0];
    float* out = (float*)d_out;
    assign_levels_v4<<<992, 256, 0, stream>>>(ann, out);
}